// Round 11
// baseline (611.075 us; speedup 1.0000x reference)
//
#include <hip/hip_runtime.h>

#define NNODES 100000
#define NEDGES 1600000
#define NBLK 391          // ceil(NNODES/256)
#define NSLICE 8
#define SLICEW 12500      // NNODES / NSLICE (exact)
#define CNTB 6250         // NEDGES/256 (exact)
#define GB0 1563          // ceil(NNODES/64) mgemm/fused blocks

typedef __attribute__((ext_vector_type(8))) short bf16x8;
typedef __attribute__((ext_vector_type(4))) float f32x4;

__device__ __forceinline__ unsigned short f2bf(float f) {
  unsigned int u = __float_as_uint(f);
  u = (u + 0x7FFFu + ((u >> 16) & 1u)) >> 16;
  return (unsigned short)u;
}
__device__ __forceinline__ float bf2f(unsigned short h) {
  return __uint_as_float(((unsigned int)h) << 16);
}

// packed fp16 helpers
__device__ __forceinline__ unsigned int pk_add_f16(unsigned int a, unsigned int b) {
  unsigned int r;
  asm("v_pk_add_f16 %0, %1, %2" : "=v"(r) : "v"(a), "v"(b));
  return r;
}
__device__ __forceinline__ unsigned int pk_max0_f16(unsigned int a, unsigned int z) {
  unsigned int r;
  asm("v_pk_max_f16 %0, %1, %2" : "=v"(r) : "v"(a), "v"(z));
  return r;
}
__device__ __forceinline__ float dot2_f16(unsigned int a, unsigned int b, float c) {
  float r;
  asm("v_dot2_f32_f16 %0, %1, %2, %3" : "=v"(r) : "v"(a), "v"(b), "v"(c));
  return r;
}

// ---------------- K1: count (unsliced) ∥ weight packs ----------------
__global__ __launch_bounds__(256)
void k1_kernel(const int* __restrict__ dst, int* __restrict__ cntD,
               const float* __restrict__ W0, const float* __restrict__ W1,
               const float* __restrict__ W2, const float* __restrict__ lw1,
               const float* __restrict__ lb1, const float* __restrict__ lw2,
               unsigned short* __restrict__ Wp0, unsigned short* __restrict__ Wp1,
               unsigned short* __restrict__ Wp2, unsigned short* __restrict__ WpE,
               float* __restrict__ biasAB, unsigned int* __restrict__ wh) {
  int b = blockIdx.x;
  int tid = threadIdx.x;
  if (b < CNTB) {
    int e = b * 256 + tid;
    if (e < NEDGES) atomicAdd(&cntD[dst[e]], 1);
    return;
  }
  int bb = b - CNTB;
  if (bb < 64) {                       // W0 pack [128,128]
    int idx = bb * 256 + tid;
    int k = idx >> 7, c = idx & 127;
    Wp0[((size_t)((k >> 5) * 128 + c)) * 32 + (k & 31)] = f2bf(W0[idx]);
  } else if (bb < 128) {               // W1 pack [128,128]
    int idx = (bb - 64) * 256 + tid;
    int k = idx >> 7, c = idx & 127;
    Wp1[((size_t)((k >> 5) * 128 + c)) * 32 + (k & 31)] = f2bf(W1[idx]);
  } else if (bb < 160) {               // W2 pack [128,64]
    int idx = (bb - 128) * 256 + tid;
    int k = idx >> 6, c = idx & 63;
    Wp2[((size_t)((k >> 5) * 64 + c)) * 32 + (k & 31)] = f2bf(W2[idx]);
  } else {                             // lw1 fused pack [64,512] + biasAB + wh
    int idx = (bb - 160) * 256 + tid;
    int k = idx >> 9, c = idx & 511;
    float v = (c < 256) ? lw1[k * 256 + c] : lw1[(64 + k) * 256 + (c - 256)];
    WpE[((size_t)((k >> 5) * 512 + c)) * 32 + (k & 31)] = f2bf(v);
    if (idx < 512) biasAB[idx] = (idx < 256) ? lb1[idx] : 0.0f;
    if (idx < 128) {
      _Float16 lo = (_Float16)lw2[idx * 2];
      _Float16 hi = (_Float16)lw2[idx * 2 + 1];
      unsigned short ulo = __builtin_bit_cast(unsigned short, lo);
      unsigned short uhi = __builtin_bit_cast(unsigned short, hi);
      wh[idx] = (unsigned int)ulo | ((unsigned int)uhi << 16);
    }
  }
}

// ---------------- scanA (+ dis) ----------------
__global__ void scanA_kernel(const int* __restrict__ cntD, int* __restrict__ blockSum,
                             float* __restrict__ dis) {
  __shared__ int sh[256];
  int v = blockIdx.x * 256 + threadIdx.x;
  int c = (v < NNODES) ? cntD[v] : 0;
  if (v < NNODES) dis[v] = rsqrtf((float)(c + 1));  // deg = in-degree + self loop
  sh[threadIdx.x] = c;
  __syncthreads();
  for (int off = 128; off; off >>= 1) {
    if (threadIdx.x < off) sh[threadIdx.x] += sh[threadIdx.x + off];
    __syncthreads();
  }
  if (threadIdx.x == 0) blockSum[blockIdx.x] = sh[0];
}

__global__ void scanB_kernel(int* __restrict__ blockSum) {
  int lane = threadIdx.x;  // 0..63
  int carry = 0;
  for (int base = 0; base < NBLK; base += 64) {
    int i = base + lane;
    int c = (i < NBLK) ? blockSum[i] : 0;
    int pre = c;
#pragma unroll
    for (int off = 1; off < 64; off <<= 1) {
      int t = __shfl_up(pre, off);
      if (lane >= off) pre += t;
    }
    int tot = __shfl(pre, 63);
    if (i < NBLK) blockSum[i] = carry + pre - c;  // exclusive
    carry += tot;
  }
}

// ---------------- agg body: aggregate one node's messages (device fn) ----------------
// PER=2: acc0/acc1 = dims {2*lane, 2*lane+1}; PER=1: acc0 = dim lane.
template <int H>
__device__ __forceinline__ void agg_node(int v, const unsigned short* __restrict__ hws,
                                         const int2* __restrict__ csrPair,
                                         const int* __restrict__ startD,
                                         const int* __restrict__ cntD,
                                         int lane, float& acc0, float& acc1) {
  constexpr int PER = H / 64;
  if constexpr (PER == 2) {
    unsigned int o = *(const unsigned int*)&hws[(size_t)v * H + lane * 2];
    acc0 = __uint_as_float(o << 16);
    acc1 = __uint_as_float(o & 0xffff0000u);
  } else {
    acc0 = bf2f(hws[(size_t)v * H + lane]);
    acc1 = 0.0f;
  }
  int s0 = startD[v], c = cntD[v];
  for (int base = 0; base < c; base += 64) {
    int rem = c - base;
    int m = rem < 64 ? rem : 64;
    int idx = 0;
    if (lane < m) idx = csrPair[s0 + base + lane].x;
    int j = 0;
    for (; j + 8 <= m; j += 8) {
      int u0 = __shfl(idx, j);
      int u1 = __shfl(idx, j + 1);
      int u2 = __shfl(idx, j + 2);
      int u3 = __shfl(idx, j + 3);
      int u4 = __shfl(idx, j + 4);
      int u5 = __shfl(idx, j + 5);
      int u6 = __shfl(idx, j + 6);
      int u7 = __shfl(idx, j + 7);
      if constexpr (PER == 2) {
        unsigned int r0 = *(const unsigned int*)&hws[(size_t)u0 * H + lane * 2];
        unsigned int r1 = *(const unsigned int*)&hws[(size_t)u1 * H + lane * 2];
        unsigned int r2 = *(const unsigned int*)&hws[(size_t)u2 * H + lane * 2];
        unsigned int r3 = *(const unsigned int*)&hws[(size_t)u3 * H + lane * 2];
        unsigned int r4 = *(const unsigned int*)&hws[(size_t)u4 * H + lane * 2];
        unsigned int r5 = *(const unsigned int*)&hws[(size_t)u5 * H + lane * 2];
        unsigned int r6 = *(const unsigned int*)&hws[(size_t)u6 * H + lane * 2];
        unsigned int r7 = *(const unsigned int*)&hws[(size_t)u7 * H + lane * 2];
        acc0 += (__uint_as_float(r0 << 16) + __uint_as_float(r1 << 16)) +
                (__uint_as_float(r2 << 16) + __uint_as_float(r3 << 16)) +
                (__uint_as_float(r4 << 16) + __uint_as_float(r5 << 16)) +
                (__uint_as_float(r6 << 16) + __uint_as_float(r7 << 16));
        acc1 += (__uint_as_float(r0 & 0xffff0000u) + __uint_as_float(r1 & 0xffff0000u)) +
                (__uint_as_float(r2 & 0xffff0000u) + __uint_as_float(r3 & 0xffff0000u)) +
                (__uint_as_float(r4 & 0xffff0000u) + __uint_as_float(r5 & 0xffff0000u)) +
                (__uint_as_float(r6 & 0xffff0000u) + __uint_as_float(r7 & 0xffff0000u));
      } else {
        float r0 = bf2f(hws[(size_t)u0 * H + lane]);
        float r1 = bf2f(hws[(size_t)u1 * H + lane]);
        float r2 = bf2f(hws[(size_t)u2 * H + lane]);
        float r3 = bf2f(hws[(size_t)u3 * H + lane]);
        float r4 = bf2f(hws[(size_t)u4 * H + lane]);
        float r5 = bf2f(hws[(size_t)u5 * H + lane]);
        float r6 = bf2f(hws[(size_t)u6 * H + lane]);
        float r7 = bf2f(hws[(size_t)u7 * H + lane]);
        acc0 += ((r0 + r1) + (r2 + r3)) + ((r4 + r5) + (r6 + r7));
      }
    }
    for (; j + 4 <= m; j += 4) {
      int u0 = __shfl(idx, j);
      int u1 = __shfl(idx, j + 1);
      int u2 = __shfl(idx, j + 2);
      int u3 = __shfl(idx, j + 3);
      if constexpr (PER == 2) {
        unsigned int r0 = *(const unsigned int*)&hws[(size_t)u0 * H + lane * 2];
        unsigned int r1 = *(const unsigned int*)&hws[(size_t)u1 * H + lane * 2];
        unsigned int r2 = *(const unsigned int*)&hws[(size_t)u2 * H + lane * 2];
        unsigned int r3 = *(const unsigned int*)&hws[(size_t)u3 * H + lane * 2];
        acc0 += __uint_as_float(r0 << 16) + __uint_as_float(r1 << 16) +
                __uint_as_float(r2 << 16) + __uint_as_float(r3 << 16);
        acc1 += __uint_as_float(r0 & 0xffff0000u) + __uint_as_float(r1 & 0xffff0000u) +
                __uint_as_float(r2 & 0xffff0000u) + __uint_as_float(r3 & 0xffff0000u);
      } else {
        float r0 = bf2f(hws[(size_t)u0 * H + lane]);
        float r1 = bf2f(hws[(size_t)u1 * H + lane]);
        float r2 = bf2f(hws[(size_t)u2 * H + lane]);
        float r3 = bf2f(hws[(size_t)u3 * H + lane]);
        acc0 += (r0 + r1) + (r2 + r3);
      }
    }
    for (; j < m; ++j) {
      int u = __shfl(idx, j);
      if constexpr (PER == 2) {
        unsigned int r = *(const unsigned int*)&hws[(size_t)u * H + lane * 2];
        acc0 += __uint_as_float(r << 16);
        acc1 += __uint_as_float(r & 0xffff0000u);
      } else {
        acc0 += bf2f(hws[(size_t)u * H + lane]);
      }
    }
  }
}

// ---------------- mgemm body (device fn, global A input) ----------------
template <int K, int HOUT, bool SCALE, bool BIAS, bool F32IN, bool F16OUT>
__device__ __forceinline__ void mgemm_body(int bid, const void* __restrict__ Xhi_v,
                                           const void* __restrict__ Xlo_v,
                                           const unsigned short* __restrict__ Wp,
                                           const float* __restrict__ dis,
                                           const float* __restrict__ bias,
                                           void* __restrict__ outv) {
  constexpr int KC = K / 32;
  const int tid = threadIdx.x;
  const int wave = tid >> 6;
  const int lane = tid & 63;
  const int lrow = lane & 15;
  const int lsub = lane >> 4;
  const int rowBase = bid * 64 + wave * 16;
  int arow = rowBase + lrow;
  if (arow > NNODES - 1) arow = NNODES - 1;
  bf16x8 ahi[KC], alo[KC];
  if constexpr (F32IN) {
    const float* xf = (const float*)Xhi_v;
#pragma unroll
    for (int kc = 0; kc < KC; ++kc) {
      float4 v0 = *(const float4*)&xf[(size_t)arow * K + kc * 32 + lsub * 8];
      float4 v1 = *(const float4*)&xf[(size_t)arow * K + kc * 32 + lsub * 8 + 4];
      float fv[8] = {v0.x, v0.y, v0.z, v0.w, v1.x, v1.y, v1.z, v1.w};
#pragma unroll
      for (int i = 0; i < 8; ++i) {
        unsigned short h = f2bf(fv[i]);
        ahi[kc][i] = (short)h;
        alo[kc][i] = (short)f2bf(fv[i] - bf2f(h));
      }
    }
  } else {
    const unsigned short* Xhi = (const unsigned short*)Xhi_v;
    const unsigned short* Xlo = (const unsigned short*)Xlo_v;
#pragma unroll
    for (int kc = 0; kc < KC; ++kc) {
      ahi[kc] = *(const bf16x8*)&Xhi[(size_t)arow * K + kc * 32 + lsub * 8];
      alo[kc] = *(const bf16x8*)&Xlo[(size_t)arow * K + kc * 32 + lsub * 8];
    }
  }
  int orow[4];
  float dis4[4];
#pragma unroll
  for (int i = 0; i < 4; ++i) {
    orow[i] = rowBase + lsub * 4 + i;
    int rc = orow[i] < NNODES ? orow[i] : NNODES - 1;
    dis4[i] = SCALE ? dis[rc] : 1.0f;
  }
  for (int ct = 0; ct < HOUT / 16; ++ct) {
    int c = ct * 16 + lrow;
    f32x4 acc = {0.f, 0.f, 0.f, 0.f};
#pragma unroll
    for (int kc = 0; kc < KC; ++kc) {
      bf16x8 b = *(const bf16x8*)&Wp[((size_t)(kc * HOUT + c)) * 32 + lsub * 8];
      acc = __builtin_amdgcn_mfma_f32_16x16x32_bf16(ahi[kc], b, acc, 0, 0, 0);
      acc = __builtin_amdgcn_mfma_f32_16x16x32_bf16(alo[kc], b, acc, 0, 0, 0);
    }
    float bb = BIAS ? bias[c] : 0.0f;
#pragma unroll
    for (int i = 0; i < 4; ++i) {
      if (orow[i] < NNODES) {
        float v = acc[i];
        if (SCALE) v *= dis4[i];
        if (BIAS) v += bb;
        if constexpr (F16OUT) {
          ((_Float16*)outv)[(size_t)orow[i] * HOUT + c] = (_Float16)v;
        } else {
          ((unsigned short*)outv)[(size_t)orow[i] * HOUT + c] = f2bf(v);
        }
      }
    }
  }
}

// ---------------- K4: mgemm L0 ∥ scanC ----------------
__global__ __launch_bounds__(256)
void mg0_scanC_kernel(const float* __restrict__ x, const unsigned short* __restrict__ Wp0,
                      const float* __restrict__ dis, unsigned short* __restrict__ P16,
                      const int* __restrict__ cntD, const int* __restrict__ blockSum,
                      int* __restrict__ startD, int* __restrict__ curD) {
  if (blockIdx.x < GB0) {
    mgemm_body<128, 128, true, false, true, false>(blockIdx.x, x, nullptr, Wp0, dis, nullptr, P16);
    return;
  }
  __shared__ int sh[256];
  int bid = blockIdx.x - GB0;
  int tid = threadIdx.x;
  int v = bid * 256 + tid;
  int c = (v < NNODES) ? cntD[v] : 0;
  sh[tid] = c;
  __syncthreads();
  for (int off = 1; off < 256; off <<= 1) {
    int t = (tid >= off) ? sh[tid - off] : 0;
    __syncthreads();
    sh[tid] += t;
    __syncthreads();
  }
  if (v < NNODES) {
    int s = blockSum[bid] + sh[tid] - c;  // exclusive prefix
    startD[v] = s;
    curD[v] = s;
  }
}

// ---------------- fill (dst-range sliced for write locality) ----------------
__global__ void fill_kernel(const int* __restrict__ src, const int* __restrict__ dst,
                            int* __restrict__ curD, int2* __restrict__ csrPair) {
  int slice = blockIdx.x & (NSLICE - 1);
  int e = (blockIdx.x >> 3) * 256 + threadIdx.x;
  if (e >= NEDGES) return;
  int d = dst[e];
  int lo = slice * SLICEW;
  if (d < lo || d >= lo + SLICEW) return;
  int s = src[e];
  int pd = atomicAdd(&curD[d], 1);
  csrPair[pd] = make_int2(s, e);
}

// ---------------- FUSED: agg(layer) -> z in LDS -> mgemm(next layer) ----------------
// H = z dims (agg width); HOUT2 = gemm output dims. Block = 64 nodes, 4 waves x 16 nodes.
template <int H, int HOUT2, bool SCALE2, bool BIAS2, bool F16OUT2>
__global__ __launch_bounds__(256)
void fused_kernel(const unsigned short* __restrict__ hws, const int2* __restrict__ csrPair,
                  const int* __restrict__ startD, const int* __restrict__ cntD,
                  const float* __restrict__ dis, const float* __restrict__ biasAgg,
                  const unsigned short* __restrict__ Wp, const float* __restrict__ biasG,
                  void* __restrict__ outv) {
  constexpr int PER = H / 64;
  constexpr int STRIDE = H + 8;   // +16B pad: phase-B row reads spread across banks
  constexpr int KC = H / 32;
  __shared__ unsigned short zhi[64 * STRIDE];
  __shared__ unsigned short zlo[64 * STRIDE];
  const int tid = threadIdx.x;
  const int wave = tid >> 6;
  const int lane = tid & 63;
  const int rowBase = blockIdx.x * 64;

  // ---- phase A: each wave aggregates 16 nodes serially, z -> LDS (split bf16) ----
  for (int i = 0; i < 16; ++i) {
    int lr = wave * 16 + i;
    int v = rowBase + lr;
    if (v >= NNODES) v = NNODES - 1;
    float acc0, acc1;
    agg_node<H>(v, hws, csrPair, startD, cntD, lane, acc0, acc1);
    float d = dis[v];
    if constexpr (PER == 2) {
      float o0 = fmaf(d, acc0, biasAgg[lane * 2]);
      float o1 = fmaf(d, acc1, biasAgg[lane * 2 + 1]);
      o0 = o0 > 0.0f ? o0 : 0.0f;
      o1 = o1 > 0.0f ? o1 : 0.0f;
      ushort2 h, l;
      h.x = f2bf(o0); l.x = f2bf(o0 - bf2f(h.x));
      h.y = f2bf(o1); l.y = f2bf(o1 - bf2f(h.y));
      *(ushort2*)&zhi[lr * STRIDE + lane * 2] = h;
      *(ushort2*)&zlo[lr * STRIDE + lane * 2] = l;
    } else {
      float o0 = fmaf(d, acc0, biasAgg[lane]);
      o0 = o0 > 0.0f ? o0 : 0.0f;
      unsigned short h = f2bf(o0);
      zhi[lr * STRIDE + lane] = h;
      zlo[lr * STRIDE + lane] = f2bf(o0 - bf2f(h));
    }
  }
  __syncthreads();

  // ---- phase B: mgemm, A-fragments from LDS ----
  const int lrow = lane & 15;
  const int lsub = lane >> 4;
  const int lr = wave * 16 + lrow;
  bf16x8 ahi[KC], alo[KC];
#pragma unroll
  for (int kc = 0; kc < KC; ++kc) {
    ahi[kc] = *(const bf16x8*)&zhi[lr * STRIDE + kc * 32 + lsub * 8];
    alo[kc] = *(const bf16x8*)&zlo[lr * STRIDE + kc * 32 + lsub * 8];
  }
  int orow[4];
  float dis4[4];
#pragma unroll
  for (int i = 0; i < 4; ++i) {
    orow[i] = rowBase + wave * 16 + lsub * 4 + i;
    int rc = orow[i] < NNODES ? orow[i] : NNODES - 1;
    dis4[i] = SCALE2 ? dis[rc] : 1.0f;
  }
  for (int ct = 0; ct < HOUT2 / 16; ++ct) {
    int c = ct * 16 + lrow;
    f32x4 acc = {0.f, 0.f, 0.f, 0.f};
#pragma unroll
    for (int kc = 0; kc < KC; ++kc) {
      bf16x8 b = *(const bf16x8*)&Wp[((size_t)(kc * HOUT2 + c)) * 32 + lsub * 8];
      acc = __builtin_amdgcn_mfma_f32_16x16x32_bf16(ahi[kc], b, acc, 0, 0, 0);
      acc = __builtin_amdgcn_mfma_f32_16x16x32_bf16(alo[kc], b, acc, 0, 0, 0);
    }
    float bb = BIAS2 ? biasG[c] : 0.0f;
#pragma unroll
    for (int i = 0; i < 4; ++i) {
      if (orow[i] < NNODES) {
        float v = acc[i];
        if (SCALE2) v *= dis4[i];
        if (BIAS2) v += bb;
        if constexpr (F16OUT2) {
          ((_Float16*)outv)[(size_t)orow[i] * HOUT2 + c] = (_Float16)v;
        } else {
          ((unsigned short*)outv)[(size_t)orow[i] * HOUT2 + c] = f2bf(v);
        }
      }
    }
  }
}

// ---------------- edge classifier: one wave per DST node, fp16 packed, fused sigmoid ----------------
__global__ __launch_bounds__(256)
void edge_kernel(const unsigned int* __restrict__ AB32,
                 const int2* __restrict__ csrPair,
                 const int* __restrict__ startD, const int* __restrict__ cntD,
                 const unsigned int* __restrict__ wh, const float* __restrict__ lb2,
                 float* __restrict__ out) {
  int gid = blockIdx.x * 256 + threadIdx.x;
  int v = gid >> 6;
  int lane = gid & 63;
  int sub = lane & 15;
  unsigned int zero = 0u;
  unsigned int bu[8], wu[8];
  {
    const unsigned int* Brow = AB32 + (size_t)v * 256 + 128 + sub * 8;
    uint4 b0 = *(const uint4*)Brow;
    uint4 b1 = *(const uint4*)(Brow + 4);
    bu[0] = b0.x; bu[1] = b0.y; bu[2] = b0.z; bu[3] = b0.w;
    bu[4] = b1.x; bu[5] = b1.y; bu[6] = b1.z; bu[7] = b1.w;
    const unsigned int* W = wh + sub * 8;
    uint4 w0 = *(const uint4*)W;
    uint4 w1 = *(const uint4*)(W + 4);
    wu[0] = w0.x; wu[1] = w0.y; wu[2] = w0.z; wu[3] = w0.w;
    wu[4] = w1.x; wu[5] = w1.y; wu[6] = w1.z; wu[7] = w1.w;
  }
  float lb = lb2[0];

  int s0 = startD[v], c = cntD[v];
  for (int base = 0; base < c; base += 64) {
    int rem = c - base;
    int m = rem < 64 ? rem : 64;
    int sj = 0, ej = 0;
    if (lane < m) {
      int2 p = csrPair[s0 + base + lane];
      sj = p.x; ej = p.y;
    }
    int g = lane >> 4;
    for (int j = 0; j < m; j += 8) {
      int ls0 = j + g, ls1 = j + 4 + g;
      int l0 = ls0 < m ? ls0 : m - 1;
      int l1 = ls1 < m ? ls1 : m - 1;
      int sA = __shfl(sj, l0);
      int eA = __shfl(ej, l0);
      int sB = __shfl(sj, l1);
      int eB = __shfl(ej, l1);
      const unsigned int* ArowA = AB32 + (size_t)(unsigned)sA * 256 + sub * 8;
      const unsigned int* ArowB = AB32 + (size_t)(unsigned)sB * 256 + sub * 8;
      uint4 a00 = *(const uint4*)ArowA;
      uint4 a01 = *(const uint4*)(ArowA + 4);
      uint4 a10 = *(const uint4*)ArowB;
      uint4 a11 = *(const uint4*)(ArowB + 4);
      unsigned int au0[8] = {a00.x, a00.y, a00.z, a00.w, a01.x, a01.y, a01.z, a01.w};
      unsigned int au1[8] = {a10.x, a10.y, a10.z, a10.w, a11.x, a11.y, a11.z, a11.w};
      float acc0 = 0.f, acc1 = 0.f;
#pragma unroll
      for (int i = 0; i < 8; ++i) {
        unsigned int h0 = pk_max0_f16(pk_add_f16(au0[i], bu[i]), zero);
        acc0 = dot2_f16(h0, wu[i], acc0);
        unsigned int h1 = pk_max0_f16(pk_add_f16(au1[i], bu[i]), zero);
        acc1 = dot2_f16(h1, wu[i], acc1);
      }
      acc0 += __shfl_xor(acc0, 1);
      acc0 += __shfl_xor(acc0, 2);
      acc0 += __shfl_xor(acc0, 4);
      acc0 += __shfl_xor(acc0, 8);
      acc1 += __shfl_xor(acc1, 1);
      acc1 += __shfl_xor(acc1, 2);
      acc1 += __shfl_xor(acc1, 4);
      acc1 += __shfl_xor(acc1, 8);
      if (ls0 < m && sub == 0) out[eA] = 1.0f / (1.0f + expf(-(acc0 + lb)));
      if (ls1 < m && sub == 0) out[eB] = 1.0f / (1.0f + expf(-(acc1 + lb)));
    }
  }
}

extern "C" void kernel_launch(void* const* d_in, const int* in_sizes, int n_in,
                              void* d_out, int out_size, void* d_ws, size_t ws_size,
                              hipStream_t stream) {
  const float* x   = (const float*)d_in[0];
  const int*   ei  = (const int*)d_in[1];
  const float* W0  = (const float*)d_in[2];
  const float* b0  = (const float*)d_in[3];
  const float* W1  = (const float*)d_in[4];
  const float* b1  = (const float*)d_in[5];
  const float* W2  = (const float*)d_in[6];
  const float* b2  = (const float*)d_in[7];
  const float* lw1 = (const float*)d_in[8];
  const float* lb1 = (const float*)d_in[9];
  const float* lw2 = (const float*)d_in[10];
  const float* lb2 = (const float*)d_in[11];
  float* out = (float*)d_out;
  const int* src = ei;
  const int* dst = ei + NEDGES;

  char* ws = (char*)d_ws;
  size_t off = 0;
  auto alloc = [&](size_t bytes) -> void* {
    void* p = ws + off;
    off += (bytes + 255) & ~(size_t)255;
    return p;
  };
  int*   cntD   = (int*)alloc((size_t)NNODES * 4);
  int*   startD = (int*)alloc((size_t)NNODES * 4);
  int*   curD   = (int*)alloc((size_t)NNODES * 4);
  float* dis    = (float*)alloc((size_t)NNODES * 4);
  int*   blockSum = (int*)alloc((size_t)NBLK * 4);
  int2*  csrPair= (int2*)alloc((size_t)NEDGES * 8);
  unsigned short* P16a = (unsigned short*)alloc((size_t)NNODES * 128 * 2);  // mg0 out / F2 out (64d)
  unsigned short* P16b = (unsigned short*)alloc((size_t)NNODES * 128 * 2);  // F1 out
  void*           AB   = alloc((size_t)NNODES * 512 * 2);                   // fp16 A|B tables
  unsigned short* Wp0  = (unsigned short*)alloc((size_t)128 * 128 * 2);
  unsigned short* Wp1  = (unsigned short*)alloc((size_t)128 * 128 * 2);
  unsigned short* Wp2  = (unsigned short*)alloc((size_t)128 * 64 * 2);
  unsigned short* WpE  = (unsigned short*)alloc((size_t)64 * 512 * 2);
  float* biasAB = (float*)alloc(512 * 4);
  unsigned int* wh = (unsigned int*)alloc(128 * 4);

  const int EB8 = NSLICE * CNTB;       // sliced fill grid
  const int AB_ = (NNODES * 64) / 256; // one wave per node (edge kernel)

  hipMemsetAsync(cntD, 0, (size_t)NNODES * 4, stream);
  k1_kernel<<<CNTB + 288, 256, 0, stream>>>(dst, cntD, W0, W1, W2, lw1, lb1, lw2,
                                            Wp0, Wp1, Wp2, WpE, biasAB, wh);
  scanA_kernel<<<NBLK, 256, 0, stream>>>(cntD, blockSum, dis);
  scanB_kernel<<<1, 64, 0, stream>>>(blockSum);
  mg0_scanC_kernel<<<GB0 + NBLK, 256, 0, stream>>>(x, Wp0, dis, P16a, cntD, blockSum, startD, curD);
  fill_kernel<<<EB8, 256, 0, stream>>>(src, dst, curD, csrPair);

  // F1: agg(P16a; b0) -> z1 (LDS) -> (z1@W1)*dis -> P16b [128d]
  fused_kernel<128, 128, true, false, false><<<GB0, 256, 0, stream>>>(
      P16a, csrPair, startD, cntD, dis, b0, Wp1, nullptr, P16b);
  // F2: agg(P16b; b1) -> z2 (LDS) -> (z2@W2)*dis -> P16a [64d]
  fused_kernel<128, 64, true, false, false><<<GB0, 256, 0, stream>>>(
      P16b, csrPair, startD, cntD, dis, b1, Wp2, nullptr, P16a);
  // F3: agg(P16a 64d; b2) -> z3 (LDS) -> z3@lw1AB + biasAB -> AB fp16 [512d]
  fused_kernel<64, 512, false, true, true><<<GB0, 256, 0, stream>>>(
      P16a, csrPair, startD, cntD, dis, b2, WpE, biasAB, AB);

  edge_kernel<<<AB_, 256, 0, stream>>>((const unsigned int*)AB, csrPair, startD, cntD, wh, lb2, out);
}

// Round 12
// 583.480 us; speedup vs baseline: 1.0473x; 1.0473x over previous
//
#include <hip/hip_runtime.h>

#define NNODES 100000
#define NEDGES 1600000
#define NBLK 391          // ceil(NNODES/256)
#define NSLICE 8
#define SLICEW 12500      // NNODES / NSLICE (exact)
#define CNTB 6250         // NEDGES/256 (exact)
#define GB0 1563          // ceil(NNODES/64) mgemm blocks

typedef __attribute__((ext_vector_type(8))) short bf16x8;
typedef __attribute__((ext_vector_type(4))) float f32x4;

__device__ __forceinline__ unsigned short f2bf(float f) {
  unsigned int u = __float_as_uint(f);
  u = (u + 0x7FFFu + ((u >> 16) & 1u)) >> 16;
  return (unsigned short)u;
}
__device__ __forceinline__ float bf2f(unsigned short h) {
  return __uint_as_float(((unsigned int)h) << 16);
}

// packed fp16 helpers
__device__ __forceinline__ unsigned int pk_add_f16(unsigned int a, unsigned int b) {
  unsigned int r;
  asm("v_pk_add_f16 %0, %1, %2" : "=v"(r) : "v"(a), "v"(b));
  return r;
}
__device__ __forceinline__ unsigned int pk_max0_f16(unsigned int a, unsigned int z) {
  unsigned int r;
  asm("v_pk_max_f16 %0, %1, %2" : "=v"(r) : "v"(a), "v"(z));
  return r;
}
__device__ __forceinline__ float dot2_f16(unsigned int a, unsigned int b, float c) {
  float r;
  asm("v_dot2_f32_f16 %0, %1, %2, %3" : "=v"(r) : "v"(a), "v"(b), "v"(c));
  return r;
}

// ---------------- K1: count (unsliced) ∥ weight packs ----------------
__global__ __launch_bounds__(256)
void k1_kernel(const int* __restrict__ dst, int* __restrict__ cntD,
               const float* __restrict__ W0, const float* __restrict__ W1,
               const float* __restrict__ W2, const float* __restrict__ lw1,
               const float* __restrict__ lb1, const float* __restrict__ lw2,
               unsigned short* __restrict__ Wp0, unsigned short* __restrict__ Wp1,
               unsigned short* __restrict__ Wp2, unsigned short* __restrict__ WpE,
               float* __restrict__ biasAB, unsigned int* __restrict__ wh) {
  int b = blockIdx.x;
  int tid = threadIdx.x;
  if (b < CNTB) {
    int e = b * 256 + tid;
    if (e < NEDGES) atomicAdd(&cntD[dst[e]], 1);
    return;
  }
  int bb = b - CNTB;
  if (bb < 64) {                       // W0 pack [128,128]
    int idx = bb * 256 + tid;
    int k = idx >> 7, c = idx & 127;
    Wp0[((size_t)((k >> 5) * 128 + c)) * 32 + (k & 31)] = f2bf(W0[idx]);
  } else if (bb < 128) {               // W1 pack [128,128]
    int idx = (bb - 64) * 256 + tid;
    int k = idx >> 7, c = idx & 127;
    Wp1[((size_t)((k >> 5) * 128 + c)) * 32 + (k & 31)] = f2bf(W1[idx]);
  } else if (bb < 160) {               // W2 pack [128,64]
    int idx = (bb - 128) * 256 + tid;
    int k = idx >> 6, c = idx & 63;
    Wp2[((size_t)((k >> 5) * 64 + c)) * 32 + (k & 31)] = f2bf(W2[idx]);
  } else {                             // lw1 fused pack [64,512] + biasAB + wh
    int idx = (bb - 160) * 256 + tid;
    int k = idx >> 9, c = idx & 511;
    float v = (c < 256) ? lw1[k * 256 + c] : lw1[(64 + k) * 256 + (c - 256)];
    WpE[((size_t)((k >> 5) * 512 + c)) * 32 + (k & 31)] = f2bf(v);
    if (idx < 512) biasAB[idx] = (idx < 256) ? lb1[idx] : 0.0f;
    if (idx < 128) {
      _Float16 lo = (_Float16)lw2[idx * 2];
      _Float16 hi = (_Float16)lw2[idx * 2 + 1];
      unsigned short ulo = __builtin_bit_cast(unsigned short, lo);
      unsigned short uhi = __builtin_bit_cast(unsigned short, hi);
      wh[idx] = (unsigned int)ulo | ((unsigned int)uhi << 16);
    }
  }
}

// ---------------- scanA (+ dis) ----------------
__global__ void scanA_kernel(const int* __restrict__ cntD, int* __restrict__ blockSum,
                             float* __restrict__ dis) {
  __shared__ int sh[256];
  int v = blockIdx.x * 256 + threadIdx.x;
  int c = (v < NNODES) ? cntD[v] : 0;
  if (v < NNODES) dis[v] = rsqrtf((float)(c + 1));  // deg = in-degree + self loop
  sh[threadIdx.x] = c;
  __syncthreads();
  for (int off = 128; off; off >>= 1) {
    if (threadIdx.x < off) sh[threadIdx.x] += sh[threadIdx.x + off];
    __syncthreads();
  }
  if (threadIdx.x == 0) blockSum[blockIdx.x] = sh[0];
}

__global__ void scanB_kernel(int* __restrict__ blockSum) {
  int lane = threadIdx.x;  // 0..63
  int carry = 0;
  for (int base = 0; base < NBLK; base += 64) {
    int i = base + lane;
    int c = (i < NBLK) ? blockSum[i] : 0;
    int pre = c;
#pragma unroll
    for (int off = 1; off < 64; off <<= 1) {
      int t = __shfl_up(pre, off);
      if (lane >= off) pre += t;
    }
    int tot = __shfl(pre, 63);
    if (i < NBLK) blockSum[i] = carry + pre - c;  // exclusive
    carry += tot;
  }
}

// ---------------- scanC: block-local scan + base -> startD/curD ----------------
__global__ void scanC_kernel(const int* __restrict__ cntD, const int* __restrict__ blockSum,
                             int* __restrict__ startD, int* __restrict__ curD) {
  __shared__ int sh[256];
  int tid = threadIdx.x;
  int v = blockIdx.x * 256 + tid;
  int c = (v < NNODES) ? cntD[v] : 0;
  sh[tid] = c;
  __syncthreads();
  for (int off = 1; off < 256; off <<= 1) {
    int t = (tid >= off) ? sh[tid - off] : 0;
    __syncthreads();
    sh[tid] += t;
    __syncthreads();
  }
  if (v < NNODES) {
    int s = blockSum[blockIdx.x] + sh[tid] - c;  // exclusive prefix
    startD[v] = s;
    curD[v] = s;
  }
}

// ---------------- mgemm body (device fn) ----------------
template <int K, int HOUT, bool SCALE, bool BIAS, bool F32IN, bool F16OUT>
__device__ __forceinline__ void mgemm_body(int bid, const void* __restrict__ Xhi_v,
                                           const void* __restrict__ Xlo_v,
                                           const unsigned short* __restrict__ Wp,
                                           const float* __restrict__ dis,
                                           const float* __restrict__ bias,
                                           void* __restrict__ outv) {
  constexpr int KC = K / 32;
  const int tid = threadIdx.x;
  const int wave = tid >> 6;
  const int lane = tid & 63;
  const int lrow = lane & 15;
  const int lsub = lane >> 4;
  const int rowBase = bid * 64 + wave * 16;
  int arow = rowBase + lrow;
  if (arow > NNODES - 1) arow = NNODES - 1;
  bf16x8 ahi[KC], alo[KC];
  if constexpr (F32IN) {
    const float* xf = (const float*)Xhi_v;
#pragma unroll
    for (int kc = 0; kc < KC; ++kc) {
      float4 v0 = *(const float4*)&xf[(size_t)arow * K + kc * 32 + lsub * 8];
      float4 v1 = *(const float4*)&xf[(size_t)arow * K + kc * 32 + lsub * 8 + 4];
      float fv[8] = {v0.x, v0.y, v0.z, v0.w, v1.x, v1.y, v1.z, v1.w};
#pragma unroll
      for (int i = 0; i < 8; ++i) {
        unsigned short h = f2bf(fv[i]);
        ahi[kc][i] = (short)h;
        alo[kc][i] = (short)f2bf(fv[i] - bf2f(h));
      }
    }
  } else {
    const unsigned short* Xhi = (const unsigned short*)Xhi_v;
    const unsigned short* Xlo = (const unsigned short*)Xlo_v;
#pragma unroll
    for (int kc = 0; kc < KC; ++kc) {
      ahi[kc] = *(const bf16x8*)&Xhi[(size_t)arow * K + kc * 32 + lsub * 8];
      alo[kc] = *(const bf16x8*)&Xlo[(size_t)arow * K + kc * 32 + lsub * 8];
    }
  }
  int orow[4];
  float dis4[4];
#pragma unroll
  for (int i = 0; i < 4; ++i) {
    orow[i] = rowBase + lsub * 4 + i;
    int rc = orow[i] < NNODES ? orow[i] : NNODES - 1;
    dis4[i] = SCALE ? dis[rc] : 1.0f;
  }
  for (int ct = 0; ct < HOUT / 16; ++ct) {
    int c = ct * 16 + lrow;
    f32x4 acc = {0.f, 0.f, 0.f, 0.f};
#pragma unroll
    for (int kc = 0; kc < KC; ++kc) {
      bf16x8 b = *(const bf16x8*)&Wp[((size_t)(kc * HOUT + c)) * 32 + lsub * 8];
      acc = __builtin_amdgcn_mfma_f32_16x16x32_bf16(ahi[kc], b, acc, 0, 0, 0);
      acc = __builtin_amdgcn_mfma_f32_16x16x32_bf16(alo[kc], b, acc, 0, 0, 0);
    }
    float bb = BIAS ? bias[c] : 0.0f;
#pragma unroll
    for (int i = 0; i < 4; ++i) {
      if (orow[i] < NNODES) {
        float v = acc[i];
        if (SCALE) v *= dis4[i];
        if (BIAS) v += bb;
        if constexpr (F16OUT) {
          ((_Float16*)outv)[(size_t)orow[i] * HOUT + c] = (_Float16)v;
        } else {
          ((unsigned short*)outv)[(size_t)orow[i] * HOUT + c] = f2bf(v);
        }
      }
    }
  }
}

template <int K, int HOUT, bool SCALE, bool BIAS, bool F32IN, bool F16OUT>
__global__ __launch_bounds__(256)
void mgemm_kernel(const void* __restrict__ Xhi_v, const void* __restrict__ Xlo_v,
                  const unsigned short* __restrict__ Wp, const float* __restrict__ dis,
                  const float* __restrict__ bias, void* __restrict__ outv) {
  mgemm_body<K, HOUT, SCALE, BIAS, F32IN, F16OUT>(blockIdx.x, Xhi_v, Xlo_v, Wp, dis, bias, outv);
}

// ---------------- FAT: mgemm L0 blocks ∥ fill blocks (independent work) ----------------
__global__ __launch_bounds__(256)
void mg0_fill_kernel(const float* __restrict__ x, const unsigned short* __restrict__ Wp0,
                     const float* __restrict__ dis, unsigned short* __restrict__ P16,
                     const int* __restrict__ src, const int* __restrict__ dst,
                     int* __restrict__ curD, int2* __restrict__ csrPair) {
  if (blockIdx.x < GB0) {
    mgemm_body<128, 128, true, false, true, false>(blockIdx.x, x, nullptr, Wp0, dis, nullptr, P16);
    return;
  }
  // fill (dst-range sliced for write locality)
  int b = blockIdx.x - GB0;
  int slice = b & (NSLICE - 1);
  int e = (b >> 3) * 256 + threadIdx.x;
  if (e >= NEDGES) return;
  int d = dst[e];
  int lo = slice * SLICEW;
  if (d < lo || d >= lo + SLICEW) return;
  int s = src[e];
  int pd = atomicAdd(&curD[d], 1);
  csrPair[pd] = make_int2(s, e);
}

// ---------------- aggregation: one wave per node, bf16 messages -> split bf16 z ----------------
template <int HOUT>
__global__ __launch_bounds__(256)
void agg_kernel(const unsigned short* __restrict__ hws, const int2* __restrict__ csrPair,
                const int* __restrict__ startA, const int* __restrict__ cnt,
                const float* __restrict__ dis, const float* __restrict__ bias,
                unsigned short* __restrict__ outHi, unsigned short* __restrict__ outLo) {
  int gid = blockIdx.x * 256 + threadIdx.x;
  int v = gid >> 6;
  int lane = gid & 63;
  constexpr int PER = HOUT / 64;
  float acc0 = 0.0f, acc1 = 0.0f;
  if constexpr (PER == 2) {
    unsigned int o = *(const unsigned int*)&hws[(size_t)v * HOUT + lane * 2];
    acc0 = __uint_as_float(o << 16);
    acc1 = __uint_as_float(o & 0xffff0000u);
  } else {
    acc0 = bf2f(hws[(size_t)v * HOUT + lane]);
  }
  int s0 = startA[v], c = cnt[v];
  for (int base = 0; base < c; base += 64) {
    int rem = c - base;
    int m = rem < 64 ? rem : 64;
    int idx = 0;
    if (lane < m) idx = csrPair[s0 + base + lane].x;
    int j = 0;
    for (; j + 8 <= m; j += 8) {   // 8-deep gather pipeline
      int u0 = __shfl(idx, j);
      int u1 = __shfl(idx, j + 1);
      int u2 = __shfl(idx, j + 2);
      int u3 = __shfl(idx, j + 3);
      int u4 = __shfl(idx, j + 4);
      int u5 = __shfl(idx, j + 5);
      int u6 = __shfl(idx, j + 6);
      int u7 = __shfl(idx, j + 7);
      if constexpr (PER == 2) {
        unsigned int r0 = *(const unsigned int*)&hws[(size_t)u0 * HOUT + lane * 2];
        unsigned int r1 = *(const unsigned int*)&hws[(size_t)u1 * HOUT + lane * 2];
        unsigned int r2 = *(const unsigned int*)&hws[(size_t)u2 * HOUT + lane * 2];
        unsigned int r3 = *(const unsigned int*)&hws[(size_t)u3 * HOUT + lane * 2];
        unsigned int r4 = *(const unsigned int*)&hws[(size_t)u4 * HOUT + lane * 2];
        unsigned int r5 = *(const unsigned int*)&hws[(size_t)u5 * HOUT + lane * 2];
        unsigned int r6 = *(const unsigned int*)&hws[(size_t)u6 * HOUT + lane * 2];
        unsigned int r7 = *(const unsigned int*)&hws[(size_t)u7 * HOUT + lane * 2];
        acc0 += (__uint_as_float(r0 << 16) + __uint_as_float(r1 << 16)) +
                (__uint_as_float(r2 << 16) + __uint_as_float(r3 << 16)) +
                (__uint_as_float(r4 << 16) + __uint_as_float(r5 << 16)) +
                (__uint_as_float(r6 << 16) + __uint_as_float(r7 << 16));
        acc1 += (__uint_as_float(r0 & 0xffff0000u) + __uint_as_float(r1 & 0xffff0000u)) +
                (__uint_as_float(r2 & 0xffff0000u) + __uint_as_float(r3 & 0xffff0000u)) +
                (__uint_as_float(r4 & 0xffff0000u) + __uint_as_float(r5 & 0xffff0000u)) +
                (__uint_as_float(r6 & 0xffff0000u) + __uint_as_float(r7 & 0xffff0000u));
      } else {
        float r0 = bf2f(hws[(size_t)u0 * HOUT + lane]);
        float r1 = bf2f(hws[(size_t)u1 * HOUT + lane]);
        float r2 = bf2f(hws[(size_t)u2 * HOUT + lane]);
        float r3 = bf2f(hws[(size_t)u3 * HOUT + lane]);
        float r4 = bf2f(hws[(size_t)u4 * HOUT + lane]);
        float r5 = bf2f(hws[(size_t)u5 * HOUT + lane]);
        float r6 = bf2f(hws[(size_t)u6 * HOUT + lane]);
        float r7 = bf2f(hws[(size_t)u7 * HOUT + lane]);
        acc0 += ((r0 + r1) + (r2 + r3)) + ((r4 + r5) + (r6 + r7));
      }
    }
    for (; j + 4 <= m; j += 4) {
      int u0 = __shfl(idx, j);
      int u1 = __shfl(idx, j + 1);
      int u2 = __shfl(idx, j + 2);
      int u3 = __shfl(idx, j + 3);
      if constexpr (PER == 2) {
        unsigned int r0 = *(const unsigned int*)&hws[(size_t)u0 * HOUT + lane * 2];
        unsigned int r1 = *(const unsigned int*)&hws[(size_t)u1 * HOUT + lane * 2];
        unsigned int r2 = *(const unsigned int*)&hws[(size_t)u2 * HOUT + lane * 2];
        unsigned int r3 = *(const unsigned int*)&hws[(size_t)u3 * HOUT + lane * 2];
        acc0 += __uint_as_float(r0 << 16) + __uint_as_float(r1 << 16) +
                __uint_as_float(r2 << 16) + __uint_as_float(r3 << 16);
        acc1 += __uint_as_float(r0 & 0xffff0000u) + __uint_as_float(r1 & 0xffff0000u) +
                __uint_as_float(r2 & 0xffff0000u) + __uint_as_float(r3 & 0xffff0000u);
      } else {
        float r0 = bf2f(hws[(size_t)u0 * HOUT + lane]);
        float r1 = bf2f(hws[(size_t)u1 * HOUT + lane]);
        float r2 = bf2f(hws[(size_t)u2 * HOUT + lane]);
        float r3 = bf2f(hws[(size_t)u3 * HOUT + lane]);
        acc0 += (r0 + r1) + (r2 + r3);
      }
    }
    for (; j < m; ++j) {
      int u = __shfl(idx, j);
      if constexpr (PER == 2) {
        unsigned int r = *(const unsigned int*)&hws[(size_t)u * HOUT + lane * 2];
        acc0 += __uint_as_float(r << 16);
        acc1 += __uint_as_float(r & 0xffff0000u);
      } else {
        acc0 += bf2f(hws[(size_t)u * HOUT + lane]);
      }
    }
  }
  float d = dis[v];
  if constexpr (PER == 2) {
    float o0 = fmaf(d, acc0, bias[lane * 2]);
    float o1 = fmaf(d, acc1, bias[lane * 2 + 1]);
    o0 = o0 > 0.0f ? o0 : 0.0f;
    o1 = o1 > 0.0f ? o1 : 0.0f;
    ushort2 h, l;
    h.x = f2bf(o0); l.x = f2bf(o0 - bf2f(h.x));
    h.y = f2bf(o1); l.y = f2bf(o1 - bf2f(h.y));
    *(ushort2*)&outHi[(size_t)v * HOUT + lane * 2] = h;
    *(ushort2*)&outLo[(size_t)v * HOUT + lane * 2] = l;
  } else {
    float o0 = fmaf(d, acc0, bias[lane]);
    o0 = o0 > 0.0f ? o0 : 0.0f;
    unsigned short h = f2bf(o0);
    outHi[(size_t)v * HOUT + lane] = h;
    outLo[(size_t)v * HOUT + lane] = f2bf(o0 - bf2f(h));
  }
}

// ---------------- edge classifier: one wave per DST node, fp16 packed, fused sigmoid ----------------
__global__ __launch_bounds__(256)
void edge_kernel(const unsigned int* __restrict__ AB32,
                 const int2* __restrict__ csrPair,
                 const int* __restrict__ startD, const int* __restrict__ cntD,
                 const unsigned int* __restrict__ wh, const float* __restrict__ lb2,
                 float* __restrict__ out) {
  int gid = blockIdx.x * 256 + threadIdx.x;
  int v = gid >> 6;
  int lane = gid & 63;
  int sub = lane & 15;
  unsigned int zero = 0u;
  unsigned int bu[8], wu[8];
  {
    const unsigned int* Brow = AB32 + (size_t)v * 256 + 128 + sub * 8;
    uint4 b0 = *(const uint4*)Brow;
    uint4 b1 = *(const uint4*)(Brow + 4);
    bu[0] = b0.x; bu[1] = b0.y; bu[2] = b0.z; bu[3] = b0.w;
    bu[4] = b1.x; bu[5] = b1.y; bu[6] = b1.z; bu[7] = b1.w;
    const unsigned int* W = wh + sub * 8;
    uint4 w0 = *(const uint4*)W;
    uint4 w1 = *(const uint4*)(W + 4);
    wu[0] = w0.x; wu[1] = w0.y; wu[2] = w0.z; wu[3] = w0.w;
    wu[4] = w1.x; wu[5] = w1.y; wu[6] = w1.z; wu[7] = w1.w;
  }
  float lb = lb2[0];

  int s0 = startD[v], c = cntD[v];
  for (int base = 0; base < c; base += 64) {
    int rem = c - base;
    int m = rem < 64 ? rem : 64;
    int sj = 0, ej = 0;
    if (lane < m) {
      int2 p = csrPair[s0 + base + lane];
      sj = p.x; ej = p.y;
    }
    int g = lane >> 4;
    for (int j = 0; j < m; j += 8) {
      int ls0 = j + g, ls1 = j + 4 + g;
      int l0 = ls0 < m ? ls0 : m - 1;
      int l1 = ls1 < m ? ls1 : m - 1;
      int sA = __shfl(sj, l0);
      int eA = __shfl(ej, l0);
      int sB = __shfl(sj, l1);
      int eB = __shfl(ej, l1);
      const unsigned int* ArowA = AB32 + (size_t)(unsigned)sA * 256 + sub * 8;
      const unsigned int* ArowB = AB32 + (size_t)(unsigned)sB * 256 + sub * 8;
      uint4 a00 = *(const uint4*)ArowA;
      uint4 a01 = *(const uint4*)(ArowA + 4);
      uint4 a10 = *(const uint4*)ArowB;
      uint4 a11 = *(const uint4*)(ArowB + 4);
      unsigned int au0[8] = {a00.x, a00.y, a00.z, a00.w, a01.x, a01.y, a01.z, a01.w};
      unsigned int au1[8] = {a10.x, a10.y, a10.z, a10.w, a11.x, a11.y, a11.z, a11.w};
      float acc0 = 0.f, acc1 = 0.f;
#pragma unroll
      for (int i = 0; i < 8; ++i) {
        unsigned int h0 = pk_max0_f16(pk_add_f16(au0[i], bu[i]), zero);
        acc0 = dot2_f16(h0, wu[i], acc0);
        unsigned int h1 = pk_max0_f16(pk_add_f16(au1[i], bu[i]), zero);
        acc1 = dot2_f16(h1, wu[i], acc1);
      }
      acc0 += __shfl_xor(acc0, 1);
      acc0 += __shfl_xor(acc0, 2);
      acc0 += __shfl_xor(acc0, 4);
      acc0 += __shfl_xor(acc0, 8);
      acc1 += __shfl_xor(acc1, 1);
      acc1 += __shfl_xor(acc1, 2);
      acc1 += __shfl_xor(acc1, 4);
      acc1 += __shfl_xor(acc1, 8);
      if (ls0 < m && sub == 0) out[eA] = 1.0f / (1.0f + expf(-(acc0 + lb)));
      if (ls1 < m && sub == 0) out[eB] = 1.0f / (1.0f + expf(-(acc1 + lb)));
    }
  }
}

extern "C" void kernel_launch(void* const* d_in, const int* in_sizes, int n_in,
                              void* d_out, int out_size, void* d_ws, size_t ws_size,
                              hipStream_t stream) {
  const float* x   = (const float*)d_in[0];
  const int*   ei  = (const int*)d_in[1];
  const float* W0  = (const float*)d_in[2];
  const float* b0  = (const float*)d_in[3];
  const float* W1  = (const float*)d_in[4];
  const float* b1  = (const float*)d_in[5];
  const float* W2  = (const float*)d_in[6];
  const float* b2  = (const float*)d_in[7];
  const float* lw1 = (const float*)d_in[8];
  const float* lb1 = (const float*)d_in[9];
  const float* lw2 = (const float*)d_in[10];
  const float* lb2 = (const float*)d_in[11];
  float* out = (float*)d_out;
  const int* src = ei;
  const int* dst = ei + NEDGES;

  char* ws = (char*)d_ws;
  size_t off = 0;
  auto alloc = [&](size_t bytes) -> void* {
    void* p = ws + off;
    off += (bytes + 255) & ~(size_t)255;
    return p;
  };
  int*   cntD   = (int*)alloc((size_t)NNODES * 4);
  int*   startD = (int*)alloc((size_t)NNODES * 4);
  int*   curD   = (int*)alloc((size_t)NNODES * 4);
  float* dis    = (float*)alloc((size_t)NNODES * 4);
  int*   blockSum = (int*)alloc((size_t)NBLK * 4);
  int2*  csrPair= (int2*)alloc((size_t)NEDGES * 8);
  unsigned short* P16  = (unsigned short*)alloc((size_t)NNODES * 128 * 2);
  unsigned short* XQhi = (unsigned short*)alloc((size_t)NNODES * 128 * 2);
  unsigned short* XQlo = (unsigned short*)alloc((size_t)NNODES * 128 * 2);
  void*           AB   = alloc((size_t)NNODES * 512 * 2);   // fp16 A|B tables
  unsigned short* Wp0  = (unsigned short*)alloc((size_t)128 * 128 * 2);
  unsigned short* Wp1  = (unsigned short*)alloc((size_t)128 * 128 * 2);
  unsigned short* Wp2  = (unsigned short*)alloc((size_t)128 * 64 * 2);
  unsigned short* WpE  = (unsigned short*)alloc((size_t)64 * 512 * 2);
  float* biasAB = (float*)alloc(512 * 4);
  unsigned int* wh = (unsigned int*)alloc(128 * 4);

  const int EB8 = NSLICE * CNTB;       // sliced fill grid
  const int AB_ = (NNODES * 64) / 256; // one wave per node

  hipMemsetAsync(cntD, 0, (size_t)NNODES * 4, stream);
  // count ∥ all weight packs
  k1_kernel<<<CNTB + 288, 256, 0, stream>>>(dst, cntD, W0, W1, W2, lw1, lb1, lw2,
                                            Wp0, Wp1, Wp2, WpE, biasAB, wh);
  scanA_kernel<<<NBLK, 256, 0, stream>>>(cntD, blockSum, dis);
  scanB_kernel<<<1, 64, 0, stream>>>(blockSum);
  scanC_kernel<<<NBLK, 256, 0, stream>>>(cntD, blockSum, startD, curD);
  // mgemm layer-0 ∥ CSR fill (independent: mg0 needs dis/x/Wp0, fill needs curD)
  mg0_fill_kernel<<<GB0 + EB8, 256, 0, stream>>>(x, Wp0, dis, P16, src, dst, curD, csrPair);

  agg_kernel<128><<<AB_, 256, 0, stream>>>(P16, csrPair, startD, cntD, dis, b0, XQhi, XQlo);
  mgemm_kernel<128, 128, true, false, false, false><<<GB0, 256, 0, stream>>>(XQhi, XQlo, Wp1, dis, nullptr, P16);
  agg_kernel<128><<<AB_, 256, 0, stream>>>(P16, csrPair, startD, cntD, dis, b1, XQhi, XQlo);
  mgemm_kernel<128, 64, true, false, false, false><<<GB0, 256, 0, stream>>>(XQhi, XQlo, Wp2, dis, nullptr, P16);
  agg_kernel<64><<<AB_, 256, 0, stream>>>(P16, csrPair, startD, cntD, dis, b2, XQhi, XQlo);

  mgemm_kernel<64, 512, false, true, false, true><<<GB0, 256, 0, stream>>>(XQhi, XQlo, WpE, nullptr, biasAB, AB);

  edge_kernel<<<AB_, 256, 0, stream>>>((const unsigned int*)AB, csrPair, startD, cntD, wh, lb2, out);
}